// Round 2
// baseline (34.346 us; speedup 1.0000x reference)
//
#include <hip/hip_runtime.h>
#include <hip/hip_bf16.h>

#define NB 32        // batch (docs)
#define NT 4096      // tokens per doc
#define NH 256       // hidden
#define NS 256       // MAX_SENTS

// ---------------------------------------------------------------------------
// Kernel 1: per-doc boundary scan.
// One block (256 threads) per doc; each thread owns 16 contiguous tokens.
// Hillis-Steele block scan over per-thread boundary counts gives each thread
// its exclusive boundary index; re-walk writes boundary token positions.
// Also writes doc_lens (int into ws for kernel 2, f32 into d_out tail).
// ---------------------------------------------------------------------------
__global__ void hie_scan_kernel(const int* __restrict__ batch_x,
                                int* __restrict__ bpos,
                                int* __restrict__ dlen,
                                float* __restrict__ dout) {
    const int b   = blockIdx.x;
    const int tid = threadIdx.x;               // 0..255
    const int* row = batch_x + (size_t)b * NT;
    const int base = tid * 16;

    int cnt = 0;
    int flags = 0;
#pragma unroll
    for (int i = 0; i < 16; ++i) {
        int f = (row[base + i] == 1);
        flags |= (f << i);
        cnt += f;
    }

    __shared__ int sm[256];
    sm[tid] = cnt;
    __syncthreads();
    // inclusive scan
    for (int off = 1; off < 256; off <<= 1) {
        int v = (tid >= off) ? sm[tid - off] : 0;
        __syncthreads();
        sm[tid] += v;
        __syncthreads();
    }

    int idx = sm[tid] - cnt;                   // exclusive prefix
#pragma unroll
    for (int i = 0; i < 16; ++i) {
        if ((flags >> i) & 1) {
            if (idx < NS) bpos[b * NS + idx] = base + i;
            ++idx;
        }
    }

    if (tid == 255) {
        int total = sm[255];
        dlen[b] = total;
        // doc_lens output (float32 region after pooled)
        dout[(size_t)NB * NS * NH + b] = (float)total;
    }
}

// ---------------------------------------------------------------------------
// Kernel 2: sentence mean-pooling.
// Grid (NS/4, NB), 256 threads = 4 waves. Each wave owns one (doc, sentence).
// Lane l loads float4 at h = 4*l (16 B/lane, fully coalesced 1 KiB per row),
// accumulates over the sentence's contiguous token range, stores float4.
// Sentences >= doc_len are zero-filled (rewrites all of poisoned d_out).
// ---------------------------------------------------------------------------
__global__ void hie_pool_kernel(const float* __restrict__ x,
                                const int* __restrict__ bpos,
                                const int* __restrict__ dlen,
                                float* __restrict__ out) {
    const int b    = blockIdx.y;
    const int s    = blockIdx.x * 4 + (threadIdx.x >> 6);
    const int lane = threadIdx.x & 63;

    float* o = out + ((size_t)b * NS + s) * NH + lane * 4;

    int L = dlen[b];
    if (L > NS) L = NS;

    if (s >= L) {
        *reinterpret_cast<float4*>(o) = make_float4(0.f, 0.f, 0.f, 0.f);
        return;
    }

    const int end   = bpos[b * NS + s];
    const int start = (s == 0) ? 0 : (bpos[b * NS + s - 1] + 1);

    const float4* p = reinterpret_cast<const float4*>(
                          x + ((size_t)b * NT + start) * NH) + lane;
    float4 acc = make_float4(0.f, 0.f, 0.f, 0.f);
    for (int t = start; t <= end; ++t) {
        float4 v = *p;
        acc.x += v.x; acc.y += v.y; acc.z += v.z; acc.w += v.w;
        p += NH / 4;
    }
    const float inv = 1.0f / (float)(end - start + 1);

    *reinterpret_cast<float4*>(o) =
        make_float4(acc.x * inv, acc.y * inv, acc.z * inv, acc.w * inv);
}

extern "C" void kernel_launch(void* const* d_in, const int* in_sizes, int n_in,
                              void* d_out, int out_size, void* d_ws, size_t ws_size,
                              hipStream_t stream) {
    const float* hie_ins = (const float*)d_in[0];
    const int*   batch_x = (const int*)d_in[1];
    float*       out     = (float*)d_out;

    // workspace partition: bpos[NB*NS] ints, dlen[NB] ints
    int* bpos = (int*)d_ws;
    int* dlen = bpos + NB * NS;

    hie_scan_kernel<<<dim3(NB), dim3(256), 0, stream>>>(batch_x, bpos, dlen, out);
    hie_pool_kernel<<<dim3(NS / 4, NB), dim3(256), 0, stream>>>(hie_ins, bpos, dlen, out);
}

// Round 3
// 29.454 us; speedup vs baseline: 1.1661x; 1.1661x over previous
//
#include <hip/hip_runtime.h>
#include <hip/hip_bf16.h>

#define NB 32        // batch (docs)
#define NT 4096      // tokens per doc
#define NH 256       // hidden
#define NS 256       // MAX_SENTS

// ---------------------------------------------------------------------------
// Fused kernel. Grid (NS/4, NB), 256 threads (4 waves).
// Phase 1: block-redundant boundary scan of batch_x row b (16 KB, L2-resident
//   after the first block of this doc). Each thread owns 16 tokens via 4×int4
//   coalesced loads; intra-wave inclusive scan via __shfl_up (no barriers),
//   cross-wave fixup via 4-entry LDS (2 barriers). Boundary positions land in
//   LDS (sm_bpos), doc_len in sm_len.
// Phase 2: each wave pools one (doc, sentence): lane l reads float4 at h=4l
//   (16 B/lane, 1 KiB/row coalesced) over the sentence's contiguous rows,
//   dual-accumulator unroll-by-2, stores float4 mean. Sentences >= doc_len
//   are zero-filled so the poisoned d_out is fully rewritten every call.
// Block x==0 also writes doc_lens (float) to the output tail.
// ---------------------------------------------------------------------------
__global__ void hie_fused_kernel(const float* __restrict__ x,
                                 const int* __restrict__ batch_x,
                                 float* __restrict__ out) {
    const int b    = blockIdx.y;
    const int tid  = threadIdx.x;              // 0..255
    const int wid  = tid >> 6;                 // wave 0..3
    const int lane = tid & 63;

    __shared__ int sm_w[5];                    // per-wave exclusive offsets + total
    __shared__ int sm_bpos[NS + 1];            // sm_bpos[0] = -1 sentinel
    __shared__ int sm_len;

    // ---- phase 1: boundary scan of this doc's flag row ----
    const int  base = tid * 16;
    const int4* rp  = reinterpret_cast<const int4*>(batch_x + (size_t)b * NT + base);
    int flags = 0, cnt = 0;
#pragma unroll
    for (int i = 0; i < 4; ++i) {
        int4 v = rp[i];
        int f0 = (v.x == 1), f1 = (v.y == 1), f2 = (v.z == 1), f3 = (v.w == 1);
        flags |= (f0 << (4 * i)) | (f1 << (4 * i + 1)) | (f2 << (4 * i + 2)) | (f3 << (4 * i + 3));
        cnt   += f0 + f1 + f2 + f3;
    }

    // intra-wave inclusive scan of cnt
    int inc = cnt;
#pragma unroll
    for (int off = 1; off < 64; off <<= 1) {
        int u = __shfl_up(inc, off, 64);
        if (lane >= off) inc += u;
    }
    if (lane == 63) sm_w[wid] = inc;           // wave totals
    __syncthreads();
    if (tid == 0) {
        int run = 0;
#pragma unroll
        for (int w = 0; w < 4; ++w) { int t = sm_w[w]; sm_w[w] = run; run += t; }
        sm_w[4]    = run;                      // doc_len (raw)
        sm_len     = run > NS ? NS : run;
        sm_bpos[0] = -1;
    }
    __syncthreads();

    int idx = (inc - cnt) + sm_w[wid];         // block-exclusive boundary index
#pragma unroll
    for (int i = 0; i < 16; ++i) {
        if ((flags >> i) & 1) {
            if (idx < NS) sm_bpos[idx + 1] = base + i;
            ++idx;
        }
    }
    __syncthreads();

    if (blockIdx.x == 0 && tid == 0)
        out[(size_t)NB * NS * NH + b] = (float)sm_w[4];   // doc_lens tail

    // ---- phase 2: pool one sentence per wave ----
    const int s = blockIdx.x * 4 + wid;
    float* o = out + ((size_t)b * NS + s) * NH + lane * 4;

    if (s >= sm_len) {
        *reinterpret_cast<float4*>(o) = make_float4(0.f, 0.f, 0.f, 0.f);
        return;
    }

    const int end   = sm_bpos[s + 1];
    const int start = sm_bpos[s] + 1;
    const int n     = end - start + 1;

    const float4* p = reinterpret_cast<const float4*>(
                          x + ((size_t)b * NT + start) * NH) + lane;
    float4 a0 = make_float4(0.f, 0.f, 0.f, 0.f);
    float4 a1 = make_float4(0.f, 0.f, 0.f, 0.f);
    int k = 0;
    for (; k + 2 <= n; k += 2) {
        float4 v0 = p[0];
        float4 v1 = p[NH / 4];
        a0.x += v0.x; a0.y += v0.y; a0.z += v0.z; a0.w += v0.w;
        a1.x += v1.x; a1.y += v1.y; a1.z += v1.z; a1.w += v1.w;
        p += 2 * (NH / 4);
    }
    if (k < n) {
        float4 v0 = p[0];
        a0.x += v0.x; a0.y += v0.y; a0.z += v0.z; a0.w += v0.w;
    }
    const float inv = 1.0f / (float)n;
    *reinterpret_cast<float4*>(o) = make_float4((a0.x + a1.x) * inv,
                                                (a0.y + a1.y) * inv,
                                                (a0.z + a1.z) * inv,
                                                (a0.w + a1.w) * inv);
}

extern "C" void kernel_launch(void* const* d_in, const int* in_sizes, int n_in,
                              void* d_out, int out_size, void* d_ws, size_t ws_size,
                              hipStream_t stream) {
    const float* hie_ins = (const float*)d_in[0];
    const int*   batch_x = (const int*)d_in[1];
    float*       out     = (float*)d_out;

    hie_fused_kernel<<<dim3(NS / 4, NB), dim3(256), 0, stream>>>(hie_ins, batch_x, out);
}